// Round 1
// baseline (300.087 us; speedup 1.0000x reference)
//
#include <hip/hip_runtime.h>

typedef unsigned short bf16_t;
typedef __attribute__((ext_vector_type(8))) short short8;
typedef __attribute__((ext_vector_type(4))) float f32x4;
typedef __attribute__((ext_vector_type(4))) unsigned short usx4;

#define T_SEQ 2048
#define NHEAD 16

__device__ __forceinline__ unsigned short f2bf(float x) {
  union { float f; unsigned u; } v; v.f = x;
  unsigned r = v.u + 0x7fffu + ((v.u >> 16) & 1u);
  return (unsigned short)(r >> 16);
}

__device__ __forceinline__ void gld_lds16(const void* g, void* l) {
  __builtin_amdgcn_global_load_lds((const __attribute__((address_space(1))) void*)g,
                                   (__attribute__((address_space(3))) void*)l, 16, 0, 0);
}

// ---------------- fp32 -> bf16 elementwise convert ----------------
__global__ __launch_bounds__(256) void cvt_bf16(const float* __restrict__ in,
                                                bf16_t* __restrict__ out, int n4) {
  int i = blockIdx.x * 256 + threadIdx.x;
  const int stride = gridDim.x * 256;
  for (; i < n4; i += stride) {
    const float4 v = ((const float4*)in)[i];
    usx4 w = { f2bf(v.x), f2bf(v.y), f2bf(v.z), f2bf(v.w) };
    ((usx4*)out)[i] = w;
  }
}

// ---------------- weight transpose + convert: W[K][N] f32 -> Wt[N][K] bf16 ----------------
__global__ __launch_bounds__(256) void wtrans(const float* __restrict__ w0, const float* __restrict__ w1,
                                              const float* __restrict__ w2, const float* __restrict__ w3,
                                              bf16_t* __restrict__ wt) {
  __shared__ float tile[32][33];
  const float* w = (blockIdx.z == 0) ? w0 : (blockIdx.z == 1) ? w1 : (blockIdx.z == 2) ? w2 : w3;
  bf16_t* o = wt + (size_t)blockIdx.z * 1024 * 1024;
  const int c = threadIdx.x & 31;
  const int r = threadIdx.x >> 5;  // 0..7
  const int k0 = blockIdx.y * 32, n0 = blockIdx.x * 32;
#pragma unroll
  for (int rr = 0; rr < 32; rr += 8)
    tile[r + rr][c] = w[(size_t)(k0 + r + rr) * 1024 + n0 + c];
  __syncthreads();
#pragma unroll
  for (int rr = 0; rr < 32; rr += 8)
    o[(size_t)(n0 + r + rr) * 1024 + k0 + c] = f2bf(tile[c][r + rr]);
}

// ---------------- 128x128 bf16 MFMA GEMM, N fixed = 1024, B pre-transposed ----------------
// MODE 0: bf16 row-major out   MODE 1: bf16 row-major out * 0.125 (Q)
// MODE 2: bf16 V^T out  [(b*16+h)*64+d][t]   MODE 3: f32 row-major out
template<int MODE>
__global__ __launch_bounds__(256) void gemm128(const bf16_t* __restrict__ A,
                                               const bf16_t* __restrict__ Bt,
                                               void* __restrict__ Cout, int K) {
  __shared__ bf16_t As[128 * 64];
  __shared__ bf16_t Bs[128 * 64];
  const int tid = threadIdx.x;
  const int lane = tid & 63;
  const int l15 = lane & 15;
  const int g = lane >> 4;
  const int wave = tid >> 6;
  const int wr = wave >> 1, wc = wave & 1;
  const int row0 = blockIdx.y * 128, col0 = blockIdx.x * 128;

  f32x4 acc[4][4];
#pragma unroll
  for (int m = 0; m < 4; ++m)
#pragma unroll
    for (int n = 0; n < 4; ++n) acc[m][n] = (f32x4){0.f, 0.f, 0.f, 0.f};

  const int r_st = tid >> 3;  // 0..31
  const int c_st = tid & 7;   // 16B chunk within a 64-elem row

  for (int kt = 0; kt < K; kt += 64) {
#pragma unroll
    for (int i = 0; i < 4; ++i) {
      const int r = r_st + i * 32;
      gld_lds16(A  + (size_t)(row0 + r) * K + kt + c_st * 8, As + (size_t)(tid + i * 256) * 8);
      gld_lds16(Bt + (size_t)(col0 + r) * K + kt + c_st * 8, Bs + (size_t)(tid + i * 256) * 8);
    }
    __syncthreads();
#pragma unroll
    for (int ks = 0; ks < 2; ++ks) {
      short8 a[4], b[4];
#pragma unroll
      for (int m = 0; m < 4; ++m)
        a[m] = *(const short8*)(As + (wr * 64 + m * 16 + l15) * 64 + ks * 32 + g * 8);
#pragma unroll
      for (int n = 0; n < 4; ++n)
        b[n] = *(const short8*)(Bs + (wc * 64 + n * 16 + l15) * 64 + ks * 32 + g * 8);
#pragma unroll
      for (int m = 0; m < 4; ++m)
#pragma unroll
        for (int n = 0; n < 4; ++n)
          acc[m][n] = __builtin_amdgcn_mfma_f32_16x16x32_bf16(a[m], b[n], acc[m][n], 0, 0, 0);
    }
    __syncthreads();
  }

  if constexpr (MODE == 0 || MODE == 1) {
    const float sc = (MODE == 1) ? 0.125f : 1.0f;
    bf16_t* C = (bf16_t*)Cout;
#pragma unroll
    for (int m = 0; m < 4; ++m) {
      const int row = row0 + wr * 64 + m * 16 + g * 4;
#pragma unroll
      for (int n = 0; n < 4; ++n) {
        const int col = col0 + wc * 64 + n * 16 + l15;
#pragma unroll
        for (int i = 0; i < 4; ++i)
          C[(size_t)(row + i) * 1024 + col] = f2bf(acc[m][n][i] * sc);
      }
    }
  } else if constexpr (MODE == 2) {
    bf16_t* C = (bf16_t*)Cout;
#pragma unroll
    for (int m = 0; m < 4; ++m) {
      const int row = row0 + wr * 64 + m * 16 + g * 4;  // global m = b*2048 + t
      const int bb = row >> 11;
      const int t = row & 2047;
#pragma unroll
      for (int n = 0; n < 4; ++n) {
        const int col = col0 + wc * 64 + n * 16 + l15;  // h*64 + d
        const int hh = col >> 6, dd = col & 63;
        usx4 w = { f2bf(acc[m][n][0]), f2bf(acc[m][n][1]), f2bf(acc[m][n][2]), f2bf(acc[m][n][3]) };
        *(usx4*)(C + (((size_t)(bb * 16 + hh) * 64 + dd) * 2048 + t)) = w;
      }
    }
  } else {
    float* C = (float*)Cout;
#pragma unroll
    for (int m = 0; m < 4; ++m) {
      const int row = row0 + wr * 64 + m * 16 + g * 4;
#pragma unroll
      for (int n = 0; n < 4; ++n) {
        const int col = col0 + wc * 64 + n * 16 + l15;
#pragma unroll
        for (int i = 0; i < 4; ++i)
          C[(size_t)(row + i) * 1024 + col] = acc[m][n][i];
      }
    }
  }
}

// ---------------- flash attention ----------------
// Qh: [B*T][1024] bf16, pre-scaled by 1/8. Kh: [B*T][1024] bf16.
// Vt: [(b*16+h)*64+d][2048] bf16.  ao out: [B*T][1024] bf16.
// Block: 4 waves; each wave owns 16 q-rows; block covers 64 q-rows of one (b,h).
// Computes S^T = mfma(A=K tiles, B=Q^T): lane holds col t_q = lane&15 (fixed),
// rows t_k = tile*16 + (lane>>4)*4 + i. Per-lane online softmax; P kept in
// registers; PV B-fragment assembled via 8 shuffles per 32-k step.
__global__ __launch_bounds__(256) void attn_fwd(const bf16_t* __restrict__ qh,
                                                const bf16_t* __restrict__ kh,
                                                const bf16_t* __restrict__ vt,
                                                bf16_t* __restrict__ ao) {
  __shared__ bf16_t Ks[64 * 64];
  __shared__ bf16_t Vs[64 * 64];
  const int tid = threadIdx.x;
  const int lane = tid & 63;
  const int l15 = lane & 15;
  const int g = lane >> 4;
  const int wave = tid >> 6;
  const int qt = blockIdx.x;   // 0..31
  const int bh = blockIdx.y;   // 0..63
  const int b = bh >> 4, h = bh & 15;

  const int tq = qt * 64 + wave * 16 + l15;
  const size_t qoff = (size_t)(b * T_SEQ + tq) * 1024 + h * 64;
  const short8 qf0 = *(const short8*)(qh + qoff + g * 8);
  const short8 qf1 = *(const short8*)(qh + qoff + 32 + g * 8);

  f32x4 ov[4];
#pragma unroll
  for (int d = 0; d < 4; ++d) ov[d] = (f32x4){0.f, 0.f, 0.f, 0.f};
  float mrun = -1e30f, lrun = 0.f;

  const size_t kbase = (size_t)b * T_SEQ * 1024 + h * 64;
  const size_t vbase = (size_t)bh * 64 * T_SEQ;

  const int r_st = tid >> 3;  // 0..31
  const int cd = tid & 7;

  for (int kv = 0; kv < T_SEQ / 64; ++kv) {
    const int t0 = kv * 64;
    // stage K tile [64 t_k][64 d] and V^T tile [64 d][64 t_k], XOR-swizzled
    // (swizzle applied on the GLOBAL source; LDS dest linear; reads un-swizzle)
#pragma unroll
    for (int i = 0; i < 2; ++i) {
      const int r = r_st + i * 32;
      const int cs = cd ^ (r & 7);
      gld_lds16(kh + kbase + (size_t)(t0 + r) * 1024 + cs * 8, Ks + (size_t)(tid + i * 256) * 8);
      gld_lds16(vt + vbase + (size_t)r * T_SEQ + t0 + cs * 8,  Vs + (size_t)(tid + i * 256) * 8);
    }
    __syncthreads();

    // S^T tiles
    f32x4 st[4];
#pragma unroll
    for (int t = 0; t < 4; ++t) st[t] = (f32x4){0.f, 0.f, 0.f, 0.f};
#pragma unroll
    for (int ks = 0; ks < 2; ++ks) {
      const short8 qf = ks ? qf1 : qf0;
#pragma unroll
      for (int t = 0; t < 4; ++t) {
        const int tk = t * 16 + l15;
        const short8 af = *(const short8*)(Ks + tk * 64 + (((ks * 4 + g) ^ (tk & 7)) * 8));
        st[t] = __builtin_amdgcn_mfma_f32_16x16x32_bf16(af, qf, st[t], 0, 0, 0);
      }
    }

    // online softmax: lane owns 16 of the 64 t_k for its t_q; reduce with lanes l^16,l^32
    float pm = -1e30f;
#pragma unroll
    for (int t = 0; t < 4; ++t)
#pragma unroll
      for (int i = 0; i < 4; ++i) pm = fmaxf(pm, st[t][i]);
    pm = fmaxf(pm, __shfl_xor(pm, 16));
    pm = fmaxf(pm, __shfl_xor(pm, 32));
    const float newm = fmaxf(mrun, pm);
    const float corr = __expf(mrun - newm);
    mrun = newm;
    float psum = 0.f;
    unsigned pk[4][2];
#pragma unroll
    for (int t = 0; t < 4; ++t) {
      const float p0 = __expf(st[t][0] - newm);
      const float p1 = __expf(st[t][1] - newm);
      const float p2 = __expf(st[t][2] - newm);
      const float p3 = __expf(st[t][3] - newm);
      psum += (p0 + p1) + (p2 + p3);
      pk[t][0] = (unsigned)f2bf(p0) | ((unsigned)f2bf(p1) << 16);
      pk[t][1] = (unsigned)f2bf(p2) | ((unsigned)f2bf(p3) << 16);
    }
    psum += __shfl_xor(psum, 16);
    psum += __shfl_xor(psum, 32);
    lrun = lrun * corr + psum;
#pragma unroll
    for (int d = 0; d < 4; ++d) {
      ov[d][0] *= corr; ov[d][1] *= corr; ov[d][2] *= corr; ov[d][3] *= corr;
    }

    // PV: out^T[d][t_q] += V^T[d][t_k] * P^T[t_k][t_q]
#pragma unroll
    for (int kb = 0; kb < 2; ++kb) {
      union { short8 v; unsigned u[4]; } bu;
#pragma unroll
      for (int jp = 0; jp < 4; ++jp) {
        // dest lane (group gg) needs t_k = kb*32 + gg*8 + {2jp, 2jp+1}:
        // source lane group = (2*gg + (jp>>1)) & 3, pack index jp&1,
        // S^T tile = kb*2 + (gg>>1)
        const int src = (((2 * g) + (jp >> 1)) & 3) * 16 + l15;
        const unsigned v0 = (unsigned)__shfl((int)pk[kb * 2][jp & 1], src);
        const unsigned v1 = (unsigned)__shfl((int)pk[kb * 2 + 1][jp & 1], src);
        bu.u[jp] = (g < 2) ? v0 : v1;
      }
#pragma unroll
      for (int d = 0; d < 4; ++d) {
        const int dr = d * 16 + l15;
        const short8 av = *(const short8*)(Vs + dr * 64 + (((kb * 4 + g) ^ (dr & 7)) * 8));
        ov[d] = __builtin_amdgcn_mfma_f32_16x16x32_bf16(av, bu.v, ov[d], 0, 0, 0);
      }
    }
    __syncthreads();
  }

  const float inv = 1.f / lrun;
  const size_t obase = (size_t)(b * T_SEQ + tq) * 1024 + h * 64;
#pragma unroll
  for (int d = 0; d < 4; ++d) {
    usx4 w = { f2bf(ov[d][0] * inv), f2bf(ov[d][1] * inv),
               f2bf(ov[d][2] * inv), f2bf(ov[d][3] * inv) };
    *(usx4*)(ao + obase + d * 16 + g * 4) = w;
  }
}

// ---------------- launch ----------------
extern "C" void kernel_launch(void* const* d_in, const int* in_sizes, int n_in,
                              void* d_out, int out_size, void* d_ws, size_t ws_size,
                              hipStream_t stream) {
  const float* k_in  = (const float*)d_in[0];
  const float* q_in  = (const float*)d_in[1];
  const float* v_in  = (const float*)d_in[2];
  const float* w_key = (const float*)d_in[3];
  const float* w_qry = (const float*)d_in[4];
  const float* w_val = (const float*)d_in[5];
  const float* w_prj = (const float*)d_in[6];

  char* ws = (char*)d_ws;
  bf16_t* xb = (bf16_t*)(ws);                      // 16 MB: bf16 input staging
  bf16_t* wt = (bf16_t*)(ws + (16u << 20));        //  8 MB: 4 transposed weights
  bf16_t* qh = (bf16_t*)(ws + (24u << 20));        // 16 MB (pre-scaled by 1/8)
  bf16_t* kh = (bf16_t*)(ws + (40u << 20));        // 16 MB
  bf16_t* vt = (bf16_t*)(ws + (56u << 20));        // 16 MB (V transposed per head)
  bf16_t* ao = (bf16_t*)(ws + (72u << 20));        // 16 MB attention output

  wtrans<<<dim3(32, 32, 4), 256, 0, stream>>>(w_key, w_qry, w_val, w_prj, wt);

  const int N4 = (8192 * 1024) / 4;
  cvt_bf16<<<2048, 256, 0, stream>>>(k_in, xb, N4);
  gemm128<0><<<dim3(8, 64), 256, 0, stream>>>(xb, wt + 0 * (1u << 20), kh, 1024);
  cvt_bf16<<<2048, 256, 0, stream>>>(q_in, xb, N4);
  gemm128<1><<<dim3(8, 64), 256, 0, stream>>>(xb, wt + 1 * (1u << 20), qh, 1024);
  cvt_bf16<<<2048, 256, 0, stream>>>(v_in, xb, N4);
  gemm128<2><<<dim3(8, 64), 256, 0, stream>>>(xb, wt + 2 * (1u << 20), vt, 1024);

  attn_fwd<<<dim3(32, 64), 256, 0, stream>>>(qh, kh, vt, ao);

  gemm128<3><<<dim3(8, 64), 256, 0, stream>>>(ao, wt + 3 * (1u << 20), d_out, 1024);
}

// Round 2
// 252.397 us; speedup vs baseline: 1.1889x; 1.1889x over previous
//
#include <hip/hip_runtime.h>

typedef unsigned short bf16_t;
typedef __attribute__((ext_vector_type(8))) short short8;
typedef __attribute__((ext_vector_type(4))) float f32x4;
typedef __attribute__((ext_vector_type(16))) float f32x16;
typedef __attribute__((ext_vector_type(4))) unsigned short usx4;

#define T_SEQ 2048
#define NHEAD 16

__device__ __forceinline__ unsigned short f2bf(float x) {
  union { float f; unsigned u; } v; v.f = x;
  unsigned r = v.u + 0x7fffu + ((v.u >> 16) & 1u);
  return (unsigned short)(r >> 16);
}

__device__ __forceinline__ void gld_lds16(const void* g, void* l) {
  __builtin_amdgcn_global_load_lds((const __attribute__((address_space(1))) void*)g,
                                   (__attribute__((address_space(3))) void*)l, 16, 0, 0);
}

// ---------------- fp32 -> bf16 elementwise convert ----------------
__global__ __launch_bounds__(256) void cvt_bf16(const float* __restrict__ in,
                                                bf16_t* __restrict__ out, int n4) {
  int i = blockIdx.x * 256 + threadIdx.x;
  const int stride = gridDim.x * 256;
  for (; i < n4; i += stride) {
    const float4 v = ((const float4*)in)[i];
    usx4 w = { f2bf(v.x), f2bf(v.y), f2bf(v.z), f2bf(v.w) };
    ((usx4*)out)[i] = w;
  }
}

// ---------------- weight transpose + convert: W[K][N] f32 -> Wt[N][K] bf16 ----------------
__global__ __launch_bounds__(256) void wtrans(const float* __restrict__ w0, const float* __restrict__ w1,
                                              const float* __restrict__ w2, const float* __restrict__ w3,
                                              bf16_t* __restrict__ wt) {
  __shared__ float tile[32][33];
  const float* w = (blockIdx.z == 0) ? w0 : (blockIdx.z == 1) ? w1 : (blockIdx.z == 2) ? w2 : w3;
  bf16_t* o = wt + (size_t)blockIdx.z * 1024 * 1024;
  const int c = threadIdx.x & 31;
  const int r = threadIdx.x >> 5;  // 0..7
  const int k0 = blockIdx.y * 32, n0 = blockIdx.x * 32;
#pragma unroll
  for (int rr = 0; rr < 32; rr += 8)
    tile[r + rr][c] = w[(size_t)(k0 + r + rr) * 1024 + n0 + c];
  __syncthreads();
#pragma unroll
  for (int rr = 0; rr < 32; rr += 8)
    o[(size_t)(n0 + r + rr) * 1024 + k0 + c] = f2bf(tile[c][r + rr]);
}

// ---------------- 128x128 bf16 MFMA GEMM, N fixed = 1024, B pre-transposed ----------------
// MODE 0: bf16 row-major out   MODE 1: bf16 row-major out * (0.125*log2e) (Q)
// MODE 2: bf16 V^T out  [(b*16+h)*64+d][t]   MODE 3: f32 row-major out
template<int MODE>
__global__ __launch_bounds__(256) void gemm128(const bf16_t* __restrict__ A,
                                               const bf16_t* __restrict__ Bt,
                                               void* __restrict__ Cout, int K) {
  __shared__ bf16_t As[128 * 64];
  __shared__ bf16_t Bs[128 * 64];
  const int tid = threadIdx.x;
  const int lane = tid & 63;
  const int l15 = lane & 15;
  const int g = lane >> 4;
  const int wave = tid >> 6;
  const int wr = wave >> 1, wc = wave & 1;
  const int row0 = blockIdx.y * 128, col0 = blockIdx.x * 128;

  f32x4 acc[4][4];
#pragma unroll
  for (int m = 0; m < 4; ++m)
#pragma unroll
    for (int n = 0; n < 4; ++n) acc[m][n] = (f32x4){0.f, 0.f, 0.f, 0.f};

  const int r_st = tid >> 3;  // 0..31
  const int c_st = tid & 7;   // 16B chunk within a 64-elem row

  for (int kt = 0; kt < K; kt += 64) {
#pragma unroll
    for (int i = 0; i < 4; ++i) {
      const int r = r_st + i * 32;
      gld_lds16(A  + (size_t)(row0 + r) * K + kt + c_st * 8, As + (size_t)(tid + i * 256) * 8);
      gld_lds16(Bt + (size_t)(col0 + r) * K + kt + c_st * 8, Bs + (size_t)(tid + i * 256) * 8);
    }
    __syncthreads();
#pragma unroll
    for (int ks = 0; ks < 2; ++ks) {
      short8 a[4], b[4];
#pragma unroll
      for (int m = 0; m < 4; ++m)
        a[m] = *(const short8*)(As + (wr * 64 + m * 16 + l15) * 64 + ks * 32 + g * 8);
#pragma unroll
      for (int n = 0; n < 4; ++n)
        b[n] = *(const short8*)(Bs + (wc * 64 + n * 16 + l15) * 64 + ks * 32 + g * 8);
#pragma unroll
      for (int m = 0; m < 4; ++m)
#pragma unroll
        for (int n = 0; n < 4; ++n)
          acc[m][n] = __builtin_amdgcn_mfma_f32_16x16x32_bf16(a[m], b[n], acc[m][n], 0, 0, 0);
    }
    __syncthreads();
  }

  if constexpr (MODE == 0 || MODE == 1) {
    const float sc = (MODE == 1) ? 0.18033688011112042f : 1.0f;  // 0.125 * log2(e)
    bf16_t* C = (bf16_t*)Cout;
#pragma unroll
    for (int m = 0; m < 4; ++m) {
      const int row = row0 + wr * 64 + m * 16 + g * 4;
#pragma unroll
      for (int n = 0; n < 4; ++n) {
        const int col = col0 + wc * 64 + n * 16 + l15;
#pragma unroll
        for (int i = 0; i < 4; ++i)
          C[(size_t)(row + i) * 1024 + col] = f2bf(acc[m][n][i] * sc);
      }
    }
  } else if constexpr (MODE == 2) {
    bf16_t* C = (bf16_t*)Cout;
#pragma unroll
    for (int m = 0; m < 4; ++m) {
      const int row = row0 + wr * 64 + m * 16 + g * 4;  // global m = b*2048 + t
      const int bb = row >> 11;
      const int t = row & 2047;
#pragma unroll
      for (int n = 0; n < 4; ++n) {
        const int col = col0 + wc * 64 + n * 16 + l15;  // h*64 + d
        const int hh = col >> 6, dd = col & 63;
        usx4 w = { f2bf(acc[m][n][0]), f2bf(acc[m][n][1]), f2bf(acc[m][n][2]), f2bf(acc[m][n][3]) };
        *(usx4*)(C + (((size_t)(bb * 16 + hh) * 64 + dd) * 2048 + t)) = w;
      }
    }
  } else {
    float* C = (float*)Cout;
#pragma unroll
    for (int m = 0; m < 4; ++m) {
      const int row = row0 + wr * 64 + m * 16 + g * 4;
#pragma unroll
      for (int n = 0; n < 4; ++n) {
        const int col = col0 + wc * 64 + n * 16 + l15;
#pragma unroll
        for (int i = 0; i < 4; ++i)
          C[(size_t)(row + i) * 1024 + col] = acc[m][n][i];
      }
    }
  }
}

// ---------------- flash attention, 32x32 MFMA, exp2-domain softmax ----------------
// Qh: [B*T][1024] bf16, pre-scaled by 0.125*log2e. Kh: [B*T][1024] bf16.
// Vt: [(b*16+h)*64+d][2048] bf16.  ao out: [B*T][1024] bf16.
// Block: 4 waves; each wave owns 32 q-rows (block 128) of one (b,h); KV tiles of 64.
// S^T = mfma32x32(K, Q^T): lane col tq=l31, rows tk=(reg&3)+8*(reg>>2)+4*half (+tile*32).
// P->bf16 via v_cvt_pk_bf16_f32, redistribution to PV B-frag via 2x permlane32_swap.
__global__ __launch_bounds__(256) void attn_fwd(const bf16_t* __restrict__ qh,
                                                const bf16_t* __restrict__ kh,
                                                const bf16_t* __restrict__ vt,
                                                bf16_t* __restrict__ ao) {
  __shared__ bf16_t smem[8192];  // Ks[64*64] | Vs[64*64]; reused as out-bounce
  bf16_t* Ks = smem;
  bf16_t* Vs = smem + 4096;
  const int tid = threadIdx.x;
  const int lane = tid & 63;
  const int l31 = lane & 31;
  const int half = lane >> 5;
  const int wave = tid >> 6;
  const int qblk = blockIdx.x;  // 0..15
  const int bh = blockIdx.y;    // 0..63
  const int b = bh >> 4, h = bh & 15;

  const int tq = qblk * 128 + wave * 32 + l31;
  const size_t qoff = (size_t)(b * T_SEQ + tq) * 1024 + h * 64;
  short8 qf[4];
#pragma unroll
  for (int ks = 0; ks < 4; ++ks)
    qf[ks] = *(const short8*)(qh + qoff + ks * 16 + half * 8);

  f32x16 ov0, ov1;
#pragma unroll
  for (int i = 0; i < 16; ++i) { ov0[i] = 0.f; ov1[i] = 0.f; }
  float mrun = -1e30f, lrun = 0.f;

  const size_t kbase = (size_t)b * T_SEQ * 1024 + h * 64;
  const size_t vbase = (size_t)bh * 64 * T_SEQ;
  const int r_st = tid >> 3;  // 0..31
  const int cd = tid & 7;

  for (int kv = 0; kv < T_SEQ / 64; ++kv) {
    const int t0 = kv * 64;
    // stage K tile [64 tk][64 d] and V^T tile [64 d][64 tk], source-XOR-swizzled
#pragma unroll
    for (int i = 0; i < 2; ++i) {
      const int r = r_st + i * 32;
      const int cs = cd ^ (r & 7);
      gld_lds16(kh + kbase + (size_t)(t0 + r) * 1024 + cs * 8, Ks + (size_t)(tid + i * 256) * 8);
      gld_lds16(vt + vbase + (size_t)r * T_SEQ + t0 + cs * 8,  Vs + (size_t)(tid + i * 256) * 8);
    }
    __syncthreads();

    // S^T: 2 tiles of 32 tk x 32 tq
    f32x16 st[2];
    __builtin_amdgcn_s_setprio(1);
#pragma unroll
    for (int t = 0; t < 2; ++t) {
#pragma unroll
      for (int i = 0; i < 16; ++i) st[t][i] = 0.f;
      const int row = t * 32 + l31;
#pragma unroll
      for (int ks = 0; ks < 4; ++ks) {
        const short8 af = *(const short8*)(Ks + row * 64 + (((ks * 2 + half) ^ (l31 & 7)) * 8));
        st[t] = __builtin_amdgcn_mfma_f32_32x32x16_bf16(af, qf[ks], st[t], 0, 0, 0);
      }
    }
    __builtin_amdgcn_s_setprio(0);

    // online softmax (log2 domain); lane covers half the 64 tk rows for col tq
    float pm = st[0][0];
#pragma unroll
    for (int i = 1; i < 16; ++i) pm = fmaxf(pm, st[0][i]);
#pragma unroll
    for (int i = 0; i < 16; ++i) pm = fmaxf(pm, st[1][i]);
    pm = fmaxf(pm, __shfl_xor(pm, 32));

    if (__any(pm > mrun + 8.f)) {  // defer-max: P bounded by 2^8
      const float newm = fmaxf(mrun, pm);
      const float corr = __builtin_amdgcn_exp2f(mrun - newm);
      mrun = newm;
      lrun *= corr;
#pragma unroll
      for (int i = 0; i < 16; ++i) { ov0[i] *= corr; ov1[i] *= corr; }
    }

    float psum = 0.f;
#pragma unroll
    for (int t = 0; t < 2; ++t)
#pragma unroll
      for (int i = 0; i < 16; ++i) {
        const float p = __builtin_amdgcn_exp2f(st[t][i] - mrun);
        st[t][i] = p;
        psum += p;
      }
    psum += __shfl_xor(psum, 32);
    lrun += psum;

    // PV: out^T[d][tq] += V^T[d][tk] * P^T[tk][tq], 4 k-steps of 16 tk
#pragma unroll
    for (int s = 0; s < 4; ++s) {
      const int t = s >> 1, base = (s & 1) * 8;
      unsigned c0, c1, c2, c3;
      asm("v_cvt_pk_bf16_f32 %0, %1, %2" : "=v"(c0) : "v"(st[t][base + 0]), "v"(st[t][base + 1]));
      asm("v_cvt_pk_bf16_f32 %0, %1, %2" : "=v"(c1) : "v"(st[t][base + 2]), "v"(st[t][base + 3]));
      asm("v_cvt_pk_bf16_f32 %0, %1, %2" : "=v"(c2) : "v"(st[t][base + 4]), "v"(st[t][base + 5]));
      asm("v_cvt_pk_bf16_f32 %0, %1, %2" : "=v"(c3) : "v"(st[t][base + 6]), "v"(st[t][base + 7]));
      // dest half h needs rows 8h+j: j<4 live in half0's c0/c1 (or c2/c3 for h=1 source regs),
      // j>=4 in half1's — one swap fills both output words (T12)
      asm("v_permlane32_swap_b32 %0, %1" : "+v"(c0), "+v"(c2));
      asm("v_permlane32_swap_b32 %0, %1" : "+v"(c1), "+v"(c3));
      union { short8 v; unsigned u[4]; } bu;
      bu.u[0] = c0; bu.u[1] = c1; bu.u[2] = c2; bu.u[3] = c3;
      __builtin_amdgcn_s_setprio(1);
#pragma unroll
      for (int dt = 0; dt < 2; ++dt) {
        const int row = dt * 32 + l31;
        const short8 av = *(const short8*)(Vs + row * 64 + (((s * 2 + half) ^ (l31 & 7)) * 8));
        if (dt == 0) ov0 = __builtin_amdgcn_mfma_f32_32x32x16_bf16(av, bu.v, ov0, 0, 0, 0);
        else         ov1 = __builtin_amdgcn_mfma_f32_32x32x16_bf16(av, bu.v, ov1, 0, 0, 0);
      }
      __builtin_amdgcn_s_setprio(0);
    }
    __syncthreads();
  }

  // epilogue: normalize, bounce through LDS (XOR-swizzled) for coalesced stores
  const float inv = 1.f / lrun;
  bf16_t* obuf = smem + wave * 2048;  // 32 rows x 64 d per wave
#pragma unroll
  for (int k = 0; k < 4; ++k) {
    usx4 w0 = { f2bf(ov0[4 * k + 0] * inv), f2bf(ov0[4 * k + 1] * inv),
                f2bf(ov0[4 * k + 2] * inv), f2bf(ov0[4 * k + 3] * inv) };
    *(usx4*)(obuf + l31 * 64 + ((k ^ (l31 & 7)) * 8) + half * 4) = w0;
    usx4 w1 = { f2bf(ov1[4 * k + 0] * inv), f2bf(ov1[4 * k + 1] * inv),
                f2bf(ov1[4 * k + 2] * inv), f2bf(ov1[4 * k + 3] * inv) };
    *(usx4*)(obuf + l31 * 64 + (((4 + k) ^ (l31 & 7)) * 8) + half * 4) = w1;
  }
  __syncthreads();
  const int r = lane >> 1;
  const int cb = (lane & 1) * 4;
  const size_t orow = (size_t)(b * T_SEQ + qblk * 128 + wave * 32 + r) * 1024 + h * 64;
#pragma unroll
  for (int c = 0; c < 4; ++c) {
    const int ch = cb + c;
    const short8 v = *(const short8*)(obuf + r * 64 + ((ch ^ (r & 7)) * 8));
    *(short8*)(ao + orow + ch * 8) = v;
  }
}

// ---------------- launch ----------------
extern "C" void kernel_launch(void* const* d_in, const int* in_sizes, int n_in,
                              void* d_out, int out_size, void* d_ws, size_t ws_size,
                              hipStream_t stream) {
  const float* k_in  = (const float*)d_in[0];
  const float* q_in  = (const float*)d_in[1];
  const float* v_in  = (const float*)d_in[2];
  const float* w_key = (const float*)d_in[3];
  const float* w_qry = (const float*)d_in[4];
  const float* w_val = (const float*)d_in[5];
  const float* w_prj = (const float*)d_in[6];

  char* ws = (char*)d_ws;
  bf16_t* xb = (bf16_t*)(ws);                      // 16 MB: bf16 input staging
  bf16_t* wt = (bf16_t*)(ws + (16u << 20));        //  8 MB: 4 transposed weights
  bf16_t* qh = (bf16_t*)(ws + (24u << 20));        // 16 MB (pre-scaled by 0.125*log2e)
  bf16_t* kh = (bf16_t*)(ws + (40u << 20));        // 16 MB
  bf16_t* vt = (bf16_t*)(ws + (56u << 20));        // 16 MB (V transposed per head)
  bf16_t* ao = (bf16_t*)(ws + (72u << 20));        // 16 MB attention output

  wtrans<<<dim3(32, 32, 4), 256, 0, stream>>>(w_key, w_qry, w_val, w_prj, wt);

  const int N4 = (8192 * 1024) / 4;
  cvt_bf16<<<2048, 256, 0, stream>>>(k_in, xb, N4);
  gemm128<0><<<dim3(8, 64), 256, 0, stream>>>(xb, wt + 0 * (1u << 20), kh, 1024);
  cvt_bf16<<<2048, 256, 0, stream>>>(q_in, xb, N4);
  gemm128<1><<<dim3(8, 64), 256, 0, stream>>>(xb, wt + 1 * (1u << 20), qh, 1024);
  cvt_bf16<<<2048, 256, 0, stream>>>(v_in, xb, N4);
  gemm128<2><<<dim3(8, 64), 256, 0, stream>>>(xb, wt + 2 * (1u << 20), vt, 1024);

  attn_fwd<<<dim3(16, 64), 256, 0, stream>>>(qh, kh, vt, ao);

  gemm128<3><<<dim3(8, 64), 256, 0, stream>>>(ao, wt + 3 * (1u << 20), d_out, 1024);
}